// Round 3
// baseline (21009.230 us; speedup 1.0000x reference)
//
#include <hip/hip_runtime.h>
#include <hip/hip_bf16.h>

typedef __attribute__((ext_vector_type(8))) short bf16x8;
typedef __attribute__((ext_vector_type(4))) float f32x4;

#define MFMA16(a,b,c) __builtin_amdgcn_mfma_f32_16x16x32_bf16((a),(b),(c),0,0,0)

// ---------------- workspace layout (byte offsets), ~46 MiB ----------------
static constexpr long OFF_WT  = 0;                    // bf16 transposed weights 46,137,344 B
static constexpr long OFF_H16 = 46137344;             // h bf16 [2 parity][4 unit][65536]
static constexpr long OFF_Y0R = OFF_H16 + 1048576;    // y0 ring bf16 [2 slot][2 dir][65536]
static constexpr long OFF_Y1R = OFF_Y0R + 524288;     // y1 ring
static constexpr long OFF_BAR = OFF_Y1R + 524288;     // barrier: cnt @+0, flag @+128

// element offsets (bf16) within weight region
static constexpr long E_FW_WXT0 = 0;        // [3072][512]
static constexpr long E_FW_WHT0 = 1572864;  // [3072][1024]
static constexpr long E_FW_WXT1 = 4718592;  // [3072][1024]
static constexpr long E_FW_WHT1 = 7864320;
static constexpr long E_BW_WXT0 = 11010048;
static constexpr long E_BW_WHT0 = 12582912;
static constexpr long E_BW_WXT1 = 15728640;
static constexpr long E_BW_WHT1 = 18874368;
static constexpr long E_FCWT    = 22020096; // [512][2048]

static constexpr long OUT_FWH = 16777216;   // fw_h [2][64][1024] in d_out (elems)
static constexpr long OUT_BWH = 16908288;

__device__ __forceinline__ float sig_(float x) {
  x = fminf(fmaxf(x, -30.f), 30.f);
  return 1.f / (1.f + __expf(-x));
}
__device__ __forceinline__ float tanh_(float x) {
  x = fminf(fmaxf(x, -15.f), 15.f);
  float e = __expf(2.f * x);
  return (e - 1.f) / (e + 1.f);
}
__device__ __forceinline__ bf16x8 bc8(uint4 v) { return __builtin_bit_cast(bf16x8, v); }
__device__ __forceinline__ unsigned short f2bfu(float f) {
  __hip_bfloat16 h = __float2bfloat16(f);
  return *(unsigned short*)&h;
}
__device__ __forceinline__ uint4 cvt8(const float* p) {
  const float4 a = ((const float4*)p)[0];
  const float4 b = ((const float4*)p)[1];
  uint4 r;
  r.x = (unsigned)f2bfu(a.x) | ((unsigned)f2bfu(a.y) << 16);
  r.y = (unsigned)f2bfu(a.z) | ((unsigned)f2bfu(a.w) << 16);
  r.z = (unsigned)f2bfu(b.x) | ((unsigned)f2bfu(b.y) << 16);
  r.w = (unsigned)f2bfu(b.z) | ((unsigned)f2bfu(b.w) << 16);
  return r;
}

// ---------------- transpose+cast: src f32 [R][C] -> dst bf16 [C][R] ----------------
__global__ void transpose_cast(const float* __restrict__ src, __hip_bfloat16* __restrict__ dst,
                               int R, int C) {
  __shared__ float tile[32][33];
  int tx = threadIdx.x, ty = threadIdx.y;
  int c0 = blockIdx.x * 32, r0 = blockIdx.y * 32;
#pragma unroll
  for (int i = 0; i < 32; i += 8) tile[ty + i][tx] = src[(long)(r0 + ty + i) * C + c0 + tx];
  __syncthreads();
#pragma unroll
  for (int i = 0; i < 32; i += 8)
    dst[(long)(c0 + ty + i) * R + r0 + tx] = __float2bfloat16(tile[tx][ty + i]);
}

// ---------------- persistent fused BiGRU ----------------
// 256 blocks (1/CU, forced by 115 KB LDS), 512 threads (8 waves = 2 m-pairs x 4 K-quarters).
// block -> (unit = blk>>6, j0 = (blk&63)*16). unit0 blocks also run the FC.
__global__ __launch_bounds__(512, 2)
void gru_persist(char* __restrict__ ws, const float* __restrict__ xf,
                 const float* __restrict__ fwbx0, const float* __restrict__ fwbh0,
                 const float* __restrict__ fwbx1, const float* __restrict__ fwbh1,
                 const float* __restrict__ bwbx0, const float* __restrict__ bwbh0,
                 const float* __restrict__ bwbx1, const float* __restrict__ bwbh1,
                 const float* __restrict__ fcb, float* __restrict__ dout) {
  __shared__ uint4 Bw[48 * 129];   // Wh slice: 48 rows x 128 chunks (+1 pad) = 99,072 B
  __shared__ float scr[4096];      // 16 KB reduce scratch

  const __hip_bfloat16* wt = (const __hip_bfloat16*)(ws + OFF_WT);
  __hip_bfloat16* h16 = (__hip_bfloat16*)(ws + OFF_H16);
  __hip_bfloat16* y0r = (__hip_bfloat16*)(ws + OFF_Y0R);
  __hip_bfloat16* y1r = (__hip_bfloat16*)(ws + OFF_Y1R);
  int* barCnt = (int*)(ws + OFF_BAR);
  int* barFlag = (int*)(ws + OFF_BAR + 128);

  const int blk = blockIdx.x;
  const int unit = blk >> 6;
  const int j0 = (blk & 63) << 4;
  const int tid = threadIdx.x;
  const int w = tid >> 6, lane = tid & 63;
  const int mp = w & 1, kq = w >> 1;
  const int rr = lane & 15, qq = lane >> 4;

  const __hip_bfloat16 *WhT, *WxT;
  const float *bx, *bh;
  int lastS;
  long dhOff;
  switch (unit) {
    case 0:  WhT = wt + E_FW_WHT0; WxT = wt + E_FW_WXT0; bx = fwbx0; bh = fwbh0; lastS = 511; dhOff = OUT_FWH; break;
    case 1:  WhT = wt + E_BW_WHT0; WxT = wt + E_BW_WXT0; bx = bwbx0; bh = bwbh0; lastS = 511; dhOff = OUT_BWH; break;
    case 2:  WhT = wt + E_FW_WHT1; WxT = wt + E_FW_WXT1; bx = fwbx1; bh = fwbh1; lastS = 512; dhOff = OUT_FWH + 65536; break;
    default: WhT = wt + E_BW_WHT1; WxT = wt + E_BW_WXT1; bx = bwbx1; bh = bwbh1; lastS = 512; dhOff = OUT_BWH + 65536; break;
  }

  // ---- load Wh slice into LDS once (48 rows x 128 uint4-chunks, stride 129)
  for (int idx = tid; idx < 48 * 128; idx += 512) {
    const int row = idx >> 7, ch = idx & 127;
    const long grow = ((long)(row >> 4) << 10) + j0 + (row & 15);
    Bw[row * 129 + ch] = *(const uint4*)(WhT + grow * 1024 + (ch << 3));
  }
  __syncthreads();

  // ---- epilogue cell: thread owns (row, colp..colp+1); h carry in registers
  const int erow = tid >> 3;
  const int colp = (tid & 7) * 2;
  const int emt = erow >> 4;
  const int eidx = (erow & 15) * 16 + colp;
  const int ej = j0 + colp;
  const float bxr0 = bx[ej], bxr1 = bx[ej + 1];
  const float bxz0 = bx[1024 + ej], bxz1 = bx[1024 + ej + 1];
  const float bxn0 = bx[2048 + ej], bxn1 = bx[2048 + ej + 1];
  const float bhr0 = bh[ej], bhr1 = bh[ej + 1];
  const float bhz0 = bh[1024 + ej], bhz1 = bh[1024 + ej + 1];
  const float bhn0 = bh[2048 + ej], bhn1 = bh[2048 + ej + 1];
  float hreg0 = 0.f, hreg1 = 0.f;

  // FC role (unit0 only)
  const int fcDir = (blk >= 32) ? 1 : 0;
  const int fcn0 = (blk & 31) << 4;
  const float fcb0 = fcb[fcn0 + colp], fcb1 = fcb[fcn0 + colp + 1];

  const int b0r = rr * 129, b1r = (16 + rr) * 129, b2r = (32 + rr) * 129;

  for (int s = 0; s <= 513; ++s) {
    const bool act = (unit < 2) ? (s < 512) : (s >= 1 && s <= 512);
    if (act) {
      const int rp = (unit < 2) ? (s & 1) : ((s - 1) & 1);
      const int wp = rp ^ 1;
      const int t = (unit == 0) ? s : (unit == 1) ? 511 - s : (unit == 2) ? s - 1 : 512 - s;
      const __hip_bfloat16* A1 = h16 + ((long)(rp * 4 + unit)) * 65536;

      f32x4 acc[4][2];
#pragma unroll
      for (int q = 0; q < 4; ++q) { acc[q][0] = (f32x4){0,0,0,0}; acc[q][1] = (f32x4){0,0,0,0}; }

      auto stepSeg1 = [&](int ks) {  // Wh half: A=h16, B=LDS
        const __hip_bfloat16* ap = A1 + (mp * 32 + rr) * 1024 + ks * 32 + qq * 8;
        bf16x8 a0 = bc8(*(const uint4*)ap);
        bf16x8 a1 = bc8(*(const uint4*)(ap + 16384));
        const int ci = ks * 4 + qq;
        bf16x8 b0 = bc8(Bw[b0r + ci]), b1 = bc8(Bw[b1r + ci]), b2 = bc8(Bw[b2r + ci]);
        acc[0][0] = MFMA16(a0, b0, acc[0][0]); acc[0][1] = MFMA16(a1, b0, acc[0][1]);
        acc[1][0] = MFMA16(a0, b1, acc[1][0]); acc[1][1] = MFMA16(a1, b1, acc[1][1]);
        acc[2][0] = MFMA16(a0, b2, acc[2][0]); acc[2][1] = MFMA16(a1, b2, acc[2][1]);
      };

      if (unit < 2) {
        const float* A2 = xf + (long)t * 512;
        auto stepSegX = [&](int ks2) {  // Wx half: A=x (f32->bf16), B=global WxT (K=512)
          const float* ap = A2 + (long)(mp * 32 + rr) * 262144 + ks2 * 32 + qq * 8;
          bf16x8 a0 = bc8(cvt8(ap));
          bf16x8 a1 = bc8(cvt8(ap + (long)16 * 262144));
          const __hip_bfloat16* bp = WxT + (long)(j0 + rr) * 512 + ks2 * 32 + qq * 8;
          bf16x8 b0 = bc8(*(const uint4*)bp);
          bf16x8 b1 = bc8(*(const uint4*)(bp + 524288));
          bf16x8 b2 = bc8(*(const uint4*)(bp + 1048576));
          acc[0][0] = MFMA16(a0, b0, acc[0][0]); acc[0][1] = MFMA16(a1, b0, acc[0][1]);
          acc[1][0] = MFMA16(a0, b1, acc[1][0]); acc[1][1] = MFMA16(a1, b1, acc[1][1]);
          acc[3][0] = MFMA16(a0, b2, acc[3][0]); acc[3][1] = MFMA16(a1, b2, acc[3][1]);
        };
        if (kq < 2) {
#pragma unroll
          for (int i = 0; i < 12; ++i) stepSeg1(kq * 12 + i);
        } else if (kq == 2) {
#pragma unroll
          for (int i = 0; i < 8; ++i) stepSeg1(24 + i);
#pragma unroll
          for (int i = 0; i < 4; ++i) stepSegX(i);
        } else {
#pragma unroll
          for (int i = 0; i < 12; ++i) stepSegX(4 + i);
        }
      } else {
        const __hip_bfloat16* A2 = y0r + ((long)((t & 1) * 2 + (unit & 1))) * 65536;
        auto stepSegR = [&](int ks2) {  // Wx half: A=y0 ring bf16, B=global WxT (K=1024)
          const __hip_bfloat16* ap = A2 + (mp * 32 + rr) * 1024 + ks2 * 32 + qq * 8;
          bf16x8 a0 = bc8(*(const uint4*)ap);
          bf16x8 a1 = bc8(*(const uint4*)(ap + 16384));
          const __hip_bfloat16* bp = WxT + (long)(j0 + rr) * 1024 + ks2 * 32 + qq * 8;
          bf16x8 b0 = bc8(*(const uint4*)bp);
          bf16x8 b1 = bc8(*(const uint4*)(bp + 1048576));
          bf16x8 b2 = bc8(*(const uint4*)(bp + 2097152));
          acc[0][0] = MFMA16(a0, b0, acc[0][0]); acc[0][1] = MFMA16(a1, b0, acc[0][1]);
          acc[1][0] = MFMA16(a0, b1, acc[1][0]); acc[1][1] = MFMA16(a1, b1, acc[1][1]);
          acc[3][0] = MFMA16(a0, b2, acc[3][0]); acc[3][1] = MFMA16(a1, b2, acc[3][1]);
        };
        if (kq < 2) {
#pragma unroll
          for (int i = 0; i < 16; ++i) stepSeg1(kq * 16 + i);
        } else {
#pragma unroll
          for (int i = 0; i < 16; ++i) stepSegR((kq - 2) * 16 + i);
        }
      }

      // ---- 4-phase K-reduction into scr[q][mt][cell]
#pragma unroll
      for (int p = 0; p < 4; ++p) {
        __syncthreads();
        if (kq == p) {
#pragma unroll
          for (int q = 0; q < 4; ++q)
#pragma unroll
            for (int m2 = 0; m2 < 2; ++m2) {
              float* sp = &scr[(q * 4 + mp * 2 + m2) * 256 + qq * 64 + rr];
              if (p == 0) {
                sp[0] = acc[q][m2][0]; sp[16] = acc[q][m2][1];
                sp[32] = acc[q][m2][2]; sp[48] = acc[q][m2][3];
              } else {
                sp[0] += acc[q][m2][0]; sp[16] += acc[q][m2][1];
                sp[32] += acc[q][m2][2]; sp[48] += acc[q][m2][3];
              }
            }
        }
      }
      __syncthreads();

      // ---- gate epilogue (thread owns 2 cells; h carry in registers)
      {
        const float R0 = scr[emt * 256 + eidx],       R1 = scr[emt * 256 + eidx + 1];
        const float Z0 = scr[(4 + emt) * 256 + eidx], Z1 = scr[(4 + emt) * 256 + eidx + 1];
        const float NH0 = scr[(8 + emt) * 256 + eidx], NH1 = scr[(8 + emt) * 256 + eidx + 1];
        const float NX0 = scr[(12 + emt) * 256 + eidx], NX1 = scr[(12 + emt) * 256 + eidx + 1];
        const float r0 = sig_(R0 + bxr0 + bhr0), r1 = sig_(R1 + bxr1 + bhr1);
        const float z0 = sig_(Z0 + bxz0 + bhz0), z1 = sig_(Z1 + bxz1 + bhz1);
        const float n0 = tanh_(NX0 + bxn0 + r0 * (NH0 + bhn0));
        const float n1 = tanh_(NX1 + bxn1 + r1 * (NH1 + bhn1));
        hreg0 = (1.f - z0) * n0 + z0 * hreg0;
        hreg1 = (1.f - z1) * n1 + z1 * hreg1;
        const unsigned hb = (unsigned)f2bfu(hreg0) | ((unsigned)f2bfu(hreg1) << 16);
        const long co = (long)erow * 1024 + ej;
        *(unsigned*)(h16 + ((long)(wp * 4 + unit)) * 65536 + co) = hb;
        __hip_bfloat16* ring = (unit < 2 ? y0r : y1r) + ((long)((t & 1) * 2 + (unit & 1))) * 65536;
        *(unsigned*)(ring + co) = hb;
        if (s == lastS) { float2 hv = {hreg0, hreg1}; *(float2*)(dout + dhOff + co) = hv; }
      }
    }

    // ---- FC (unit0 blocks): out[:, t, :] for t = s-2 (fw) / 513-s (bw)
    if (unit == 0 && s >= 2) {
      const int tfc = fcDir ? 513 - s : s - 2;
      const __hip_bfloat16* Afc = y1r + ((long)((tfc & 1) * 2 + fcDir)) * 65536;
      const __hip_bfloat16* Bfc = wt + E_FCWT + (long)fcDir * 1024;
      f32x4 fa0 = {0,0,0,0}, fa1 = {0,0,0,0};
#pragma unroll
      for (int i = 0; i < 8; ++i) {
        const int ks = kq * 8 + i;
        const __hip_bfloat16* ap = Afc + (mp * 32 + rr) * 1024 + ks * 32 + qq * 8;
        bf16x8 a0 = bc8(*(const uint4*)ap);
        bf16x8 a1 = bc8(*(const uint4*)(ap + 16384));
        bf16x8 b = bc8(*(const uint4*)(Bfc + (long)(fcn0 + rr) * 2048 + ks * 32 + qq * 8));
        fa0 = MFMA16(a0, b, fa0);
        fa1 = MFMA16(a1, b, fa1);
      }
#pragma unroll
      for (int p = 0; p < 4; ++p) {
        __syncthreads();
        if (kq == p) {
          float* sp0 = &scr[(mp * 2) * 256 + qq * 64 + rr];
          float* sp1 = &scr[(mp * 2 + 1) * 256 + qq * 64 + rr];
          if (p == 0) {
            sp0[0] = fa0[0]; sp0[16] = fa0[1]; sp0[32] = fa0[2]; sp0[48] = fa0[3];
            sp1[0] = fa1[0]; sp1[16] = fa1[1]; sp1[32] = fa1[2]; sp1[48] = fa1[3];
          } else {
            sp0[0] += fa0[0]; sp0[16] += fa0[1]; sp0[32] += fa0[2]; sp0[48] += fa0[3];
            sp1[0] += fa1[0]; sp1[16] += fa1[1]; sp1[32] += fa1[2]; sp1[48] += fa1[3];
          }
        }
      }
      __syncthreads();
      {
        const float v0 = scr[emt * 256 + eidx], v1 = scr[emt * 256 + eidx + 1];
        float* po = dout + (long)erow * 262144 + (long)tfc * 512 + fcn0 + colp;
        const bool first = fcDir ? (tfc >= 256) : (tfc <= 255);
        if (first) { po[0] = v0 + fcb0; po[1] = v1 + fcb1; }
        else       { po[0] += v0;       po[1] += v1; }
      }
    }

    // ---- device-wide barrier (agent scope; LDS weights survive L2 inv)
    __syncthreads();
    if (tid == 0) {
      __threadfence();  // release: drain + wbl2
      const int tgt = s + 1;
      const int old = __hip_atomic_fetch_add(barCnt, 1, __ATOMIC_RELAXED, __HIP_MEMORY_SCOPE_AGENT);
      if (old == 256 * (s + 1) - 1) {
        __hip_atomic_store(barFlag, tgt, __ATOMIC_RELAXED, __HIP_MEMORY_SCOPE_AGENT);
      } else {
        int it = 0;
        while (__hip_atomic_load(barFlag, __ATOMIC_RELAXED, __HIP_MEMORY_SCOPE_AGENT) < tgt) {
          if (++it > 16384) break;  // bounded: degrade to wrong answer, never hang
          __builtin_amdgcn_s_sleep(2);
        }
      }
      __threadfence();  // acquire: inv L1/L2 before next step's reads
    }
    __syncthreads();
  }
}

extern "C" void kernel_launch(void* const* d_in, const int* in_sizes, int n_in,
                              void* d_out, int out_size, void* d_ws, size_t ws_size,
                              hipStream_t stream) {
  (void)in_sizes; (void)n_in; (void)out_size; (void)ws_size;
  char* ws = (char*)d_ws;
  const float* x = (const float*)d_in[0];
  __hip_bfloat16* wt = (__hip_bfloat16*)(ws + OFF_WT);

  // zero h16 + rings + barrier state (contiguous)
  hipMemsetAsync(ws + OFF_H16, 0, 1048576 + 524288 + 524288 + 256, stream);

  // transpose-cast weights: src [K][3072] -> dst [3072][K] (and fc [2048][512] -> [512][2048])
  dim3 tb(32, 8);
  transpose_cast<<<dim3(96, 16), tb, 0, stream>>>((const float*)d_in[1],  wt + E_FW_WXT0, 512,  3072);
  transpose_cast<<<dim3(96, 32), tb, 0, stream>>>((const float*)d_in[2],  wt + E_FW_WHT0, 1024, 3072);
  transpose_cast<<<dim3(96, 32), tb, 0, stream>>>((const float*)d_in[5],  wt + E_FW_WXT1, 1024, 3072);
  transpose_cast<<<dim3(96, 32), tb, 0, stream>>>((const float*)d_in[6],  wt + E_FW_WHT1, 1024, 3072);
  transpose_cast<<<dim3(96, 16), tb, 0, stream>>>((const float*)d_in[9],  wt + E_BW_WXT0, 512,  3072);
  transpose_cast<<<dim3(96, 32), tb, 0, stream>>>((const float*)d_in[10], wt + E_BW_WHT0, 1024, 3072);
  transpose_cast<<<dim3(96, 32), tb, 0, stream>>>((const float*)d_in[13], wt + E_BW_WXT1, 1024, 3072);
  transpose_cast<<<dim3(96, 32), tb, 0, stream>>>((const float*)d_in[14], wt + E_BW_WHT1, 1024, 3072);
  transpose_cast<<<dim3(16, 64), tb, 0, stream>>>((const float*)d_in[17], wt + E_FCWT,    2048, 512);

  gru_persist<<<256, 512, 0, stream>>>(
      ws, x,
      (const float*)d_in[3],  (const float*)d_in[4],
      (const float*)d_in[7],  (const float*)d_in[8],
      (const float*)d_in[11], (const float*)d_in[12],
      (const float*)d_in[15], (const float*)d_in[16],
      (const float*)d_in[18], (float*)d_out);
}